// Round 8
// baseline (235.431 us; speedup 1.0000x reference)
//
#include <hip/hip_runtime.h>

#define N_NODES 20000
#define N_EDGES 200000
#define DIM 128
#define T_STEPS 8
#define N_TILES (N_NODES / 16)          // 1250
#define SCAN_N (N_NODES + 1)            // 20001
#define SCAN_BLKS ((SCAN_N + 1023) / 1024)  // 20
#define LSTR 140   // LDS row stride in shorts: 70 dwords; 70%32=6 -> q*280%32={0,24,16,8}, conflict-free b16 writes

typedef short short8 __attribute__((ext_vector_type(8)));
typedef float f32x4 __attribute__((ext_vector_type(4)));

static __device__ __forceinline__ unsigned short f2bf(float f) {
  union { float f; unsigned u; } v; v.f = f;
  unsigned r = v.u + 0x7fffu + ((v.u >> 16) & 1u);   // RNE
  return (unsigned short)(r >> 16);
}
static __device__ __forceinline__ float fast_tanh(float x) {
  float e = __expf(2.f * x);           // inf-safe: x>>0 -> 1, x<<0 -> -1
  return 1.f - 2.f / (e + 1.f);
}
static __device__ __forceinline__ float fast_sig(float x) {
  return 1.f / (1.f + __expf(-x));
}

// ---------------------------------------------------------------------------
// Repack the five 128x128 fp32 weight matrices (row-major W[k][n]) into bf16
// MFMA B-fragment order: pack[m][((nt*4+ks)*64+lane)*8+j] = bf16(W[k][n]),
// n = nt*16 + (lane&15), k = ks*32 + (lane>>4)*8 + j.
// Slots: 0=Wenc 1=Wz 2=Uz 3=Wh 4=Uh.
// ---------------------------------------------------------------------------
__global__ void repack5(const float* __restrict__ w0,
                        const float* __restrict__ w1,
                        const float* __restrict__ w2,
                        const float* __restrict__ w3,
                        const float* __restrict__ w4,
                        unsigned short* __restrict__ pack) {
  int i = blockIdx.x * blockDim.x + threadIdx.x;
  if (i >= 5 * 16384) return;
  int m = i >> 14, r = i & 16383;
  int j = r & 7, lane = (r >> 3) & 63, ks = (r >> 9) & 3, nt = (r >> 11) & 7;
  int n = nt * 16 + (lane & 15);
  int k = ks * 32 + (lane >> 4) * 8 + j;
  const float* w = (m == 0) ? w0 : (m == 1) ? w1 : (m == 2) ? w2
                 : (m == 3) ? w3 : w4;
  pack[i] = f2bf(w[k * DIM + n]);
}

// ------------------------- CSR build: bucket by dst ------------------------
__global__ void hist_k(const int* __restrict__ dst, int* __restrict__ counts) {
  int i = blockIdx.x * blockDim.x + threadIdx.x;
  if (i >= N_EDGES) return;
  atomicAdd(&counts[dst[i]], 1);
}

__global__ void scan1_k(const int* __restrict__ counts,
                        int* __restrict__ base, int* __restrict__ bsum) {
  __shared__ int ls[256];
  int tid = threadIdx.x;
  int i0 = blockIdx.x * 1024 + tid * 4;
  int v[4], ts = 0;
#pragma unroll
  for (int r = 0; r < 4; r++) {
    v[r] = (i0 + r < SCAN_N) ? counts[i0 + r] : 0;
    ts += v[r];
  }
  ls[tid] = ts; __syncthreads();
#pragma unroll
  for (int off = 1; off < 256; off <<= 1) {
    int x = (tid >= off) ? ls[tid - off] : 0;
    __syncthreads(); ls[tid] += x; __syncthreads();
  }
  int run = ls[tid] - ts;
  if (tid == 255) bsum[blockIdx.x] = ls[255];
#pragma unroll
  for (int r = 0; r < 4; r++) {
    if (i0 + r < SCAN_N) base[i0 + r] = run;
    run += v[r];
  }
}

__global__ void scan2_k(int* __restrict__ bsum) {
  __shared__ int ls[256];
  int tid = threadIdx.x;
  int v = (tid < SCAN_BLKS) ? bsum[tid] : 0;
  ls[tid] = v; __syncthreads();
#pragma unroll
  for (int off = 1; off < 256; off <<= 1) {
    int x = (tid >= off) ? ls[tid - off] : 0;
    __syncthreads(); ls[tid] += x; __syncthreads();
  }
  if (tid < SCAN_BLKS) bsum[tid] = ls[tid] - v;
}

__global__ void scan3_k(int* __restrict__ base, const int* __restrict__ bsum) {
  int i = blockIdx.x * blockDim.x + threadIdx.x;
  if (i < SCAN_N) base[i] += bsum[i >> 10];
}

// epack = src | rel<<15 | t<<23  (src<32768, rel<256, t<8)
__global__ void fill_k(const int* __restrict__ src, const int* __restrict__ dst,
                       const int* __restrict__ etype, const int* __restrict__ etime,
                       const float* __restrict__ ew,
                       const int* __restrict__ base, int* __restrict__ cursor,
                       unsigned* __restrict__ epack, float* __restrict__ sw) {
  int i = blockIdx.x * blockDim.x + threadIdx.x;
  if (i >= N_EDGES) return;
  int d = dst[i];
  int pos = base[d] + atomicAdd(&cursor[d], 1);
  epack[pos] = (unsigned)src[i] | ((unsigned)etype[i] << 15) | ((unsigned)etime[i] << 23);
  sw[pos] = ew[i];
}

// ---------------------------------------------------------------------------
// Gather: one wave per dst node; 8 per-t accumulator pairs in registers,
// predicated FMA on wave-uniform t. Writes all 8 agg[t][node] rows (bf16),
// including zeros -> no memset needed.
// ---------------------------------------------------------------------------
__global__ void gather_k(const int* __restrict__ base,
                         const unsigned* __restrict__ epack,
                         const float* __restrict__ sw,
                         const float* __restrict__ nemb,
                         const float* __restrict__ remb,
                         unsigned short* __restrict__ aggb) {
  int lane = threadIdx.x & 63;
  int node = (blockIdx.x * blockDim.x + threadIdx.x) >> 6;   // 0..N_NODES-1
  int s0 = base[node], s1 = base[node + 1];
  float ax[T_STEPS], ay[T_STEPS];
#pragma unroll
  for (int tt = 0; tt < T_STEPS; tt++) { ax[tt] = 0.f; ay[tt] = 0.f; }
  for (int i = s0; i < s1; i++) {
    unsigned u = epack[i];
    float w = sw[i];
    int s = u & 0x7fff, rt = (u >> 15) & 0xff, t = u >> 23;
    float2 sv = ((const float2*)(nemb + (size_t)s * DIM))[lane];
    float2 rv = ((const float2*)(remb + (size_t)rt * DIM))[lane];
    float m0 = sv.x * rv.x * w;
    float m1 = sv.y * rv.y * w;
#pragma unroll
    for (int tt = 0; tt < T_STEPS; tt++) {
      ax[tt] += (t == tt) ? m0 : 0.f;
      ay[tt] += (t == tt) ? m1 : 0.f;
    }
  }
#pragma unroll
  for (int tt = 0; tt < T_STEPS; tt++) {
    ushort2 o; o.x = f2bf(ax[tt]); o.y = f2bf(ay[tt]);
    ((ushort2*)(aggb + ((size_t)tt * N_NODES + node) * DIM))[lane] = o;
  }
}

// ---------------------------------------------------------------------------
// Encoder prepass: H[t] = fast_tanh(agg[t] @ Wenc), one wave per (tile,t)
// (10000 fully-independent waves -> activation VALU runs at full util).
// Output in MFMA A-fragment order: Hbuf[(((tile*8+t)*4+ks)*64+lane)*8+j].
// MFMA 16x16x32_bf16 layouts (HW-verified): A: m=lane&15,k=quad*8+j;
// B: n=lane&15,k=quad*8+j;  C/D: col=lane&15, row=quad*4+reg.
// C->A layout via LDS, stride LSTR=140 shorts (conflict-free writes).
// ---------------------------------------------------------------------------
__global__ void enc_H(const unsigned short* __restrict__ aggb,
                      const unsigned short* __restrict__ pack,
                      unsigned short* __restrict__ Hbuf) {
  __shared__ unsigned short hl[4][16 * LSTR];
  int lane = threadIdx.x & 63;
  int w = blockIdx.x * 4 + (threadIdx.x >> 6);  // 0..9999
  int t = w & 7, tile = w >> 3;
  int q = lane >> 4, l15 = lane & 15;
  int row0 = tile * 16;

  f32x4 acc[8];
#pragma unroll
  for (int nt = 0; nt < 8; nt++) acc[nt] = (f32x4){0.f, 0.f, 0.f, 0.f};
#pragma unroll
  for (int ks = 0; ks < 4; ks++) {
    short8 a = *(const short8*)(aggb +
        ((size_t)t * N_NODES + row0 + l15) * DIM + ks * 32 + q * 8);
#pragma unroll
    for (int nt = 0; nt < 8; nt++) {
      short8 b = *(const short8*)(pack + ((nt * 4 + ks) * 64 + lane) * 8);
      acc[nt] = __builtin_amdgcn_mfma_f32_16x16x32_bf16(a, b, acc[nt], 0, 0, 0);
    }
  }
  unsigned short* h = hl[threadIdx.x >> 6];
#pragma unroll
  for (int nt = 0; nt < 8; nt++)
#pragma unroll
    for (int r = 0; r < 4; r++)
      h[(q * 4 + r) * LSTR + nt * 16 + l15] = f2bf(fast_tanh(acc[nt][r]));
  __syncthreads();
#pragma unroll
  for (int ks = 0; ks < 4; ks++) {
    short8 v = *(const short8*)&h[l15 * LSTR + ks * 32 + q * 8];
    *(short8*)(Hbuf + (((size_t)(tile * T_STEPS + t) * 4 + ks) * 64 + lane) * 8) = v;
  }
}

// ---------------------------------------------------------------------------
// GRU recurrence: one block per 16-row tile, 8 waves; wave nt owns one
// 16-column tile. Pinned B-frags: Wz,Uz,Wh,Uh for its nt = 16 x short8 =
// 64 VGPRs (launch_bounds(512,4) -> 128-VGPR cap makes the compiler keep
// them resident; zero in-loop weight traffic). Per step:
//   S -> double-buffered LDS (stride 140), hA global loads issued BEFORE the
//   barrier (latency overlap), ONE barrier, sA b128 reads,
//   zpre = bz + H@Wz + S@Uz ; cpre = bh + H@Wh + S@Uh   (16 MFMAs)
//   S = (1-sig(zpre))*S + sig(zpre)*fast_tanh(cpre)
// Dbuf WAR safety: writes of buffer X at step t+2 are after barrier(t+1),
// which is after all reads of X at step t.
// ---------------------------------------------------------------------------
__launch_bounds__(512, 4)
__global__ void recur(const unsigned short* __restrict__ Hbuf,
                      const unsigned short* __restrict__ pack,
                      const float* __restrict__ bz,
                      const float* __restrict__ bh,
                      float* __restrict__ out) {
  __shared__ unsigned short Sb[2][16 * LSTR];
  int lane = threadIdx.x & 63;
  int nt = threadIdx.x >> 6;        // wave id = column tile, 0..7
  int tile = blockIdx.x;
  int q = lane >> 4, l15 = lane & 15;
  int row0 = tile * 16;

  short8 wz[4], uz[4], wh[4], uh[4];
#pragma unroll
  for (int ks = 0; ks < 4; ks++) {
    int fo = ((nt * 4 + ks) * 64 + lane) * 8;
    wz[ks] = *(const short8*)(pack + 16384 * 1 + fo);
    uz[ks] = *(const short8*)(pack + 16384 * 2 + fo);
    wh[ks] = *(const short8*)(pack + 16384 * 3 + fo);
    uh[ks] = *(const short8*)(pack + 16384 * 4 + fo);
  }
  float bzv = bz[nt * 16 + l15];
  float bhv = bh[nt * 16 + l15];

  f32x4 stC = (f32x4){0.f, 0.f, 0.f, 0.f};

  for (int t = 0; t < T_STEPS; t++) {
    unsigned short* sB = Sb[t & 1];
#pragma unroll
    for (int r = 0; r < 4; r++)
      sB[(q * 4 + r) * LSTR + nt * 16 + l15] = f2bf(stC[r]);

    // H A-frags from global (issued before barrier -> overlaps LDS drain)
    short8 hA[4];
#pragma unroll
    for (int ks = 0; ks < 4; ks++)
      hA[ks] = *(const short8*)(Hbuf +
          (((size_t)(tile * T_STEPS + t) * 4 + ks) * 64 + lane) * 8);

    __syncthreads();

    short8 sA[4];
#pragma unroll
    for (int ks = 0; ks < 4; ks++)
      sA[ks] = *(const short8*)&sB[l15 * LSTR + ks * 32 + q * 8];

    f32x4 accz = (f32x4){bzv, bzv, bzv, bzv};
    f32x4 accc = (f32x4){bhv, bhv, bhv, bhv};
#pragma unroll
    for (int ks = 0; ks < 4; ks++) {
      accz = __builtin_amdgcn_mfma_f32_16x16x32_bf16(hA[ks], wz[ks], accz, 0, 0, 0);
      accz = __builtin_amdgcn_mfma_f32_16x16x32_bf16(sA[ks], uz[ks], accz, 0, 0, 0);
      accc = __builtin_amdgcn_mfma_f32_16x16x32_bf16(hA[ks], wh[ks], accc, 0, 0, 0);
      accc = __builtin_amdgcn_mfma_f32_16x16x32_bf16(sA[ks], uh[ks], accc, 0, 0, 0);
    }
#pragma unroll
    for (int r = 0; r < 4; r++) {
      float z = fast_sig(accz[r]);
      float c = fast_tanh(accc[r]);
      stC[r] = (1.f - z) * stC[r] + z * c;
    }
  }

  // final state -> out (fp32, C-layout positions)
#pragma unroll
  for (int r = 0; r < 4; r++)
    out[(size_t)(row0 + q * 4 + r) * DIM + nt * 16 + l15] = stC[r];
}

extern "C" void kernel_launch(void* const* d_in, const int* in_sizes, int n_in,
                              void* d_out, int out_size, void* d_ws, size_t ws_size,
                              hipStream_t stream) {
  const int* eidx  = (const int*)d_in[0];
  const int* src   = eidx;
  const int* dst   = eidx + N_EDGES;
  const int* etype = (const int*)d_in[1];
  const int* etime = (const int*)d_in[2];
  const float* ew   = (const float*)d_in[3];
  const float* nemb = (const float*)d_in[4];
  const float* remb = (const float*)d_in[5];
  const float* Wenc = (const float*)d_in[6];
  const float* Wz   = (const float*)d_in[7];
  const float* Uz   = (const float*)d_in[8];
  const float* Wh   = (const float*)d_in[9];
  const float* Uh   = (const float*)d_in[10];
  const float* bz   = (const float*)d_in[11];
  const float* bh   = (const float*)d_in[12];
  // d_in[13] = num_times (constant 8 for this problem's fixed shapes)

  // ws layout
  unsigned short* aggb = (unsigned short*)d_ws;                    // 41 MB
  unsigned short* Hbuf = aggb + (size_t)T_STEPS * N_NODES * DIM;   // 41 MB
  int* counts = (int*)(Hbuf + (size_t)T_STEPS * N_NODES * DIM);    // SCAN_N
  int* cursor = counts + SCAN_N;                                   // N_NODES
  int* bsum   = cursor + N_NODES;                                  // 64
  int* base   = bsum + 64;                                         // SCAN_N
  unsigned* epack = (unsigned*)(base + SCAN_N);                    // E
  float* sw   = (float*)(epack + N_EDGES);                         // E
  unsigned short* pack = (unsigned short*)(sw + N_EDGES);          // 5*16384
  float* outp = (float*)d_out;

  hipMemsetAsync(counts, 0, (size_t)(SCAN_N + N_NODES) * sizeof(int), stream);
  repack5<<<(5 * 16384 + 255) / 256, 256, 0, stream>>>(Wenc, Wz, Uz, Wh, Uh, pack);
  hist_k<<<(N_EDGES + 255) / 256, 256, 0, stream>>>(dst, counts);
  scan1_k<<<SCAN_BLKS, 256, 0, stream>>>(counts, base, bsum);
  scan2_k<<<1, 256, 0, stream>>>(bsum);
  scan3_k<<<(SCAN_N + 255) / 256, 256, 0, stream>>>(base, bsum);
  fill_k<<<(N_EDGES + 255) / 256, 256, 0, stream>>>(src, dst, etype, etime, ew,
                                                    base, cursor, epack, sw);
  gather_k<<<N_NODES / 4, 256, 0, stream>>>(base, epack, sw, nemb, remb, aggb);
  enc_H<<<(N_TILES * T_STEPS) / 4, 256, 0, stream>>>(aggb, pack, Hbuf);
  recur<<<N_TILES, 512, 0, stream>>>(Hbuf, pack, bz, bh, outp);
}